// Round 9
// baseline (517.838 us; speedup 1.0000x reference)
//
#include <hip/hip_runtime.h>
#include <hip/hip_bf16.h>
#include <math.h>

#define NUM_USER 50000
#define NUM_ITEM 30000
#define N_NODES  80000
#define N_EDGES  1000000
#define FEAT_DIM 768
#define DLAT 128
#define DID  64
#define NEG_SLOPE 0.01f

#define SCAN_NB ((N_NODES + 255) / 256)   // 313 blocks

__device__ __forceinline__ float leaky(float v) { return v >= 0.f ? v : NEG_SLOPE * v; }

__device__ __forceinline__ float wave_reduce_sum(float v) {
#pragma unroll
    for (int off = 32; off > 0; off >>= 1) v += __shfl_xor(v, off, 64);
    return v;
}

// f32 -> bf16 RNE and back
__device__ __forceinline__ unsigned short f2bf(float f) {
    unsigned int u = __float_as_uint(f);
    unsigned int r = u + 0x7fffu + ((u >> 16) & 1u);
    return (unsigned short)(r >> 16);
}
__device__ __forceinline__ float bf2f(unsigned short h) {
    return __uint_as_float(((unsigned int)h) << 16);
}

typedef __attribute__((ext_vector_type(8))) short short8v;
typedef __attribute__((ext_vector_type(4))) float f32x4;

// split 8 f32 into bf16 hi/lo packed int4s and store to LDS
__device__ __forceinline__ void split_store8(
    float4 a, float4 b, unsigned short* dh, unsigned short* dl)
{
    float v[8] = {a.x, a.y, a.z, a.w, b.x, b.y, b.z, b.w};
    unsigned int ph[4], pl[4];
#pragma unroll
    for (int i = 0; i < 4; i++) {
        unsigned short h0 = f2bf(v[2*i]),   l0 = f2bf(v[2*i]   - bf2f(h0));
        unsigned short h1 = f2bf(v[2*i+1]), l1 = f2bf(v[2*i+1] - bf2f(h1));
        ph[i] = (unsigned int)h0 | ((unsigned int)h1 << 16);
        pl[i] = (unsigned int)l0 | ((unsigned int)l1 << 16);
    }
    *(int4*)dh = make_int4((int)ph[0], (int)ph[1], (int)ph[2], (int)ph[3]);
    *(int4*)dl = make_int4((int)pl[0], (int)pl[1], (int)pl[2], (int)pl[3]);
}

// ---------------- generic weight transpose + hi/lo split ----------------
// W is [KK][NN] (k-major); output Wt [NN][KK] hi/lo bf16.
template<int KK, int NN>
__global__ __launch_bounds__(256) void wt_prep_g_kernel(
    const float* __restrict__ W, unsigned short* __restrict__ Wh,
    unsigned short* __restrict__ Wl)
{
    int id = blockIdx.x * 256 + threadIdx.x;
    if (id < KK * NN) {
        int n = id / KK, k = id % KK;
        float v = W[(size_t)k * NN + n];
        unsigned short h = f2bf(v);
        Wh[id] = h;
        Wl[id] = f2bf(v - bf2f(h));
    }
}

// =======================================================================
// conv via split-bf16 MFMA: O[80000,NC] = X[80000,(ldx)] @ W[K,NC]
// (NC==K). Block 64 rows, 4 waves (128: 2x2 wave grid / 64: 4x1).
// A staged f32->hi/lo in LDS; B fragments read from global Wt (L2-hot).
// =======================================================================
template<int K, int NC>
__global__ __launch_bounds__(256) void conv_mfma_kernel(
    const float* __restrict__ X, int ldx,
    const unsigned short* __restrict__ Wth, const unsigned short* __restrict__ Wtl,
    float* __restrict__ O, int ldo)
{
    constexpr int NW = NC / 64;            // wave-grid cols: 2 or 1
    constexpr int MW = 4 / NW;             // wave-grid rows: 2 or 4
    constexpr int WROWS = 64 / MW;         // 32 or 16
    constexpr int MF = WROWS / 16;         // 2 or 1
    constexpr int KSTEPS = K / 32;
    constexpr int KP = K + 8;

    __shared__ unsigned short sAh[64][KP];
    __shared__ unsigned short sAl[64][KP];

    const int tid = threadIdx.x;
    const int lane = tid & 63;
    const int w = tid >> 6;
    const int wr = w / NW, wc = w % NW;
    const int r0 = blockIdx.x * 64;

    // ---- stage A tile (64 x K) f32 -> bf16 hi/lo ----
#pragma unroll
    for (int it = 0; it < K / 32; it++) {
        int slot = tid + it * 256;              // 64*K/8 slots total
        int row = slot / (K / 8);
        int k8 = (slot % (K / 8)) * 8;
        const float4* p = (const float4*)(X + (size_t)(r0 + row) * ldx + k8);
        split_store8(p[0], p[1], &sAh[row][k8], &sAl[row][k8]);
    }
    __syncthreads();

    f32x4 acc[MF][4];
#pragma unroll
    for (int m = 0; m < MF; m++)
#pragma unroll
        for (int n = 0; n < 4; n++) acc[m][n] = (f32x4){0.f, 0.f, 0.f, 0.f};

#pragma unroll
    for (int ks = 0; ks < KSTEPS; ks++) {
        int klane = ks * 32 + (lane >> 4) * 8;
        short8v ah[MF], al[MF];
#pragma unroll
        for (int m = 0; m < MF; m++) {
            int row = wr * WROWS + m * 16 + (lane & 15);
            ah[m] = *(const short8v*)&sAh[row][klane];
            al[m] = *(const short8v*)&sAl[row][klane];
        }
#pragma unroll
        for (int n = 0; n < 4; n++) {
            int col = wc * 64 + n * 16 + (lane & 15);
            short8v bh = *(const short8v*)(Wth + (size_t)col * K + klane);
            short8v bl = *(const short8v*)(Wtl + (size_t)col * K + klane);
#pragma unroll
            for (int m = 0; m < MF; m++) {
                acc[m][n] = __builtin_amdgcn_mfma_f32_16x16x32_bf16(ah[m], bh, acc[m][n], 0, 0, 0);
                acc[m][n] = __builtin_amdgcn_mfma_f32_16x16x32_bf16(ah[m], bl, acc[m][n], 0, 0, 0);
                acc[m][n] = __builtin_amdgcn_mfma_f32_16x16x32_bf16(al[m], bh, acc[m][n], 0, 0, 0);
            }
        }
    }

#pragma unroll
    for (int m = 0; m < MF; m++) {
        int rbase = r0 + wr * WROWS + m * 16 + (lane >> 4) * 4;
#pragma unroll
        for (int n = 0; n < 4; n++) {
            int col = wc * 64 + n * 16 + (lane & 15);
#pragma unroll
            for (int q = 0; q < 4; q++)
                O[(size_t)(rbase + q) * ldo + col] = acc[m][n][q];
        }
    }
}

// =======================================================================
// combine via split-bf16 MFMA (N=64):
// out[n][out_off+c] = leaky(H@G + g_b + leaky(X@L + lin_b) + id_emb)
// Block 64 rows, 4 waves x (16 rows x 64 cols).
// =======================================================================
template<int K>
__global__ __launch_bounds__(256) void combine_mfma_kernel(
    const float* __restrict__ H, int ldh,
    const float* __restrict__ X, int ldx,
    const unsigned short* __restrict__ Gth, const unsigned short* __restrict__ Gtl,
    const unsigned short* __restrict__ Lth, const unsigned short* __restrict__ Ltl,
    const float* __restrict__ g_b, const float* __restrict__ lin_b,
    const float* __restrict__ id_emb, float* __restrict__ out, int out_off)
{
    constexpr int KSTEPS = K / 32;
    constexpr int KP = K + 8;

    __shared__ unsigned short sHh[64][KP];
    __shared__ unsigned short sHl[64][KP];
    __shared__ unsigned short sXh[64][KP];
    __shared__ unsigned short sXl[64][KP];

    const int tid = threadIdx.x;
    const int lane = tid & 63;
    const int wr = tid >> 6;               // 0..3, 16 rows each
    const int r0 = blockIdx.x * 64;

#pragma unroll
    for (int it = 0; it < K / 32; it++) {
        int slot = tid + it * 256;
        int row = slot / (K / 8);
        int k8 = (slot % (K / 8)) * 8;
        const float4* ph = (const float4*)(H + (size_t)(r0 + row) * ldh + k8);
        split_store8(ph[0], ph[1], &sHh[row][k8], &sHl[row][k8]);
        const float4* px = (const float4*)(X + (size_t)(r0 + row) * ldx + k8);
        split_store8(px[0], px[1], &sXh[row][k8], &sXl[row][k8]);
    }
    __syncthreads();

    f32x4 accG[4], accL[4];
#pragma unroll
    for (int n = 0; n < 4; n++) {
        accG[n] = (f32x4){0.f, 0.f, 0.f, 0.f};
        accL[n] = (f32x4){0.f, 0.f, 0.f, 0.f};
    }

#pragma unroll
    for (int ks = 0; ks < KSTEPS; ks++) {
        int klane = ks * 32 + (lane >> 4) * 8;
        int row = wr * 16 + (lane & 15);
        short8v hh = *(const short8v*)&sHh[row][klane];
        short8v hl = *(const short8v*)&sHl[row][klane];
        short8v xh = *(const short8v*)&sXh[row][klane];
        short8v xl = *(const short8v*)&sXl[row][klane];
#pragma unroll
        for (int n = 0; n < 4; n++) {
            int col = n * 16 + (lane & 15);
            short8v gh = *(const short8v*)(Gth + (size_t)col * K + klane);
            short8v gl = *(const short8v*)(Gtl + (size_t)col * K + klane);
            short8v lh = *(const short8v*)(Lth + (size_t)col * K + klane);
            short8v ll = *(const short8v*)(Ltl + (size_t)col * K + klane);
            accG[n] = __builtin_amdgcn_mfma_f32_16x16x32_bf16(hh, gh, accG[n], 0, 0, 0);
            accG[n] = __builtin_amdgcn_mfma_f32_16x16x32_bf16(hh, gl, accG[n], 0, 0, 0);
            accG[n] = __builtin_amdgcn_mfma_f32_16x16x32_bf16(hl, gh, accG[n], 0, 0, 0);
            accL[n] = __builtin_amdgcn_mfma_f32_16x16x32_bf16(xh, lh, accL[n], 0, 0, 0);
            accL[n] = __builtin_amdgcn_mfma_f32_16x16x32_bf16(xh, ll, accL[n], 0, 0, 0);
            accL[n] = __builtin_amdgcn_mfma_f32_16x16x32_bf16(xl, lh, accL[n], 0, 0, 0);
        }
    }

    int rbase = r0 + wr * 16 + (lane >> 4) * 4;
#pragma unroll
    for (int n = 0; n < 4; n++) {
        int col = n * 16 + (lane & 15);
        float gb = g_b[col], lb = lin_b[col];
#pragma unroll
        for (int q = 0; q < 4; q++) {
            int gr = rbase + q;
            float xhv = leaky(accL[n][q] + lb) + id_emb[(size_t)gr * DID + col];
            float v = leaky(accG[n][q] + gb + xhv);
            out[(size_t)gr * (2 * DID) + out_off + col] = v;
        }
    }
}

// =======================================================================
// MLP via split-bf16 MFMA (verified): xout = tanh(F @ W + b), item rows.
// =======================================================================
__global__ __launch_bounds__(256) void mlp_mfma_kernel(
    const float* __restrict__ F,
    const unsigned short* __restrict__ Wh, const unsigned short* __restrict__ Wl,
    const float* __restrict__ bias, float* __restrict__ xout)
{
    __shared__ unsigned short sAh[64][72];
    __shared__ unsigned short sAl[64][72];
    __shared__ unsigned short sWh[128][72];
    __shared__ unsigned short sWlo[128][72];

    const int tid = threadIdx.x;
    const int lane = tid & 63;
    const int w = tid >> 6;
    const int wr = w >> 1, wc = w & 1;
    const int r0 = blockIdx.x * 64;

    f32x4 acc[2][4];
#pragma unroll
    for (int m = 0; m < 2; m++)
#pragma unroll
        for (int n = 0; n < 4; n++) acc[m][n] = (f32x4){0.f, 0.f, 0.f, 0.f};

    for (int kc = 0; kc < FEAT_DIM; kc += 64) {
#pragma unroll
        for (int it = 0; it < 2; it++) {
            int slot = tid + it * 256;
            int row = slot >> 3;
            int k8 = (slot & 7) * 8;
            int gr = r0 + row;
            float4 a = make_float4(0.f, 0.f, 0.f, 0.f), b = a;
            if (gr < NUM_ITEM) {
                const float4* p = (const float4*)(F + (size_t)gr * FEAT_DIM + kc + k8);
                a = p[0]; b = p[1];
            }
            split_store8(a, b, &sAh[row][k8], &sAl[row][k8]);
        }
#pragma unroll
        for (int it = 0; it < 4; it++) {
            int slot = tid + it * 256;
            int n = slot >> 3;
            int k8 = (slot & 7) * 8;
            *(int4*)&sWh[n][k8]  = *(const int4*)(Wh + (size_t)n * FEAT_DIM + kc + k8);
            *(int4*)&sWlo[n][k8] = *(const int4*)(Wl + (size_t)n * FEAT_DIM + kc + k8);
        }
        __syncthreads();

#pragma unroll
        for (int k0 = 0; k0 < 64; k0 += 32) {
            int klane = k0 + (lane >> 4) * 8;
            short8v ah[2], al[2], bh[4], bl[4];
#pragma unroll
            for (int m = 0; m < 2; m++) {
                int row = wr * 32 + m * 16 + (lane & 15);
                ah[m] = *(const short8v*)&sAh[row][klane];
                al[m] = *(const short8v*)&sAl[row][klane];
            }
#pragma unroll
            for (int n = 0; n < 4; n++) {
                int col = wc * 64 + n * 16 + (lane & 15);
                bh[n] = *(const short8v*)&sWh[col][klane];
                bl[n] = *(const short8v*)&sWlo[col][klane];
            }
#pragma unroll
            for (int m = 0; m < 2; m++)
#pragma unroll
                for (int n = 0; n < 4; n++) {
                    acc[m][n] = __builtin_amdgcn_mfma_f32_16x16x32_bf16(ah[m], bh[n], acc[m][n], 0, 0, 0);
                    acc[m][n] = __builtin_amdgcn_mfma_f32_16x16x32_bf16(ah[m], bl[n], acc[m][n], 0, 0, 0);
                    acc[m][n] = __builtin_amdgcn_mfma_f32_16x16x32_bf16(al[m], bh[n], acc[m][n], 0, 0, 0);
                }
        }
        __syncthreads();
    }

#pragma unroll
    for (int m = 0; m < 2; m++) {
        int rbase = r0 + wr * 32 + m * 16 + (lane >> 4) * 4;
#pragma unroll
        for (int n = 0; n < 4; n++) {
            int col = wc * 64 + n * 16 + (lane & 15);
            float bv = bias[col];
#pragma unroll
            for (int q = 0; q < 4; q++) {
                int gr = rbase + q;
                if (gr < NUM_ITEM)
                    xout[(size_t)gr * DLAT + col] = tanhf(acc[m][n][q] + bv);
            }
        }
    }
}

// ---------------- in-place row L2 normalize (D=128), wave per row ----------------
__global__ __launch_bounds__(256) void l2norm_rows_kernel(float* __restrict__ x)
{
    int wid = blockIdx.x * 4 + (threadIdx.x >> 6);
    if (wid >= N_NODES) return;
    int lane = threadIdx.x & 63;
    float* row = x + (size_t)wid * DLAT;
    float v0 = row[lane], v1 = row[lane + 64];
    float s = wave_reduce_sum(v0 * v0 + v1 * v1);
    float inv = 1.0f / fmaxf(sqrtf(s), 1e-12f);
    row[lane] = v0 * inv;
    row[lane + 64] = v1 * inv;
}

// ---------------- degree count ----------------
__global__ __launch_bounds__(256) void count_kernel(
    const int* __restrict__ src, const int* __restrict__ dst,
    int* __restrict__ deg_out, int* __restrict__ cnt_in)
{
    int e = blockIdx.x * 256 + threadIdx.x;
    if (e < N_EDGES) {
        atomicAdd(&deg_out[src[e]], 1);
        atomicAdd(&cnt_in[dst[e]], 1);
    }
}

// ---------------- 3-phase multi-block exclusive scan ----------------
__global__ __launch_bounds__(256) void scan_local_kernel(
    const int* __restrict__ cnt, int* __restrict__ rowptr, int* __restrict__ blocksum)
{
    __shared__ int wsum[4];
    int gid = blockIdx.x * 256 + threadIdx.x;
    int lane = threadIdx.x & 63, w = threadIdx.x >> 6;
    int orig = (gid < N_NODES) ? cnt[gid] : 0;
    int v = orig;
#pragma unroll
    for (int off = 1; off < 64; off <<= 1) {
        int u = __shfl_up(v, off, 64);
        if (lane >= off) v += u;
    }
    if (lane == 63) wsum[w] = v;
    __syncthreads();
    int woff = 0;
#pragma unroll
    for (int i = 0; i < 4; i++) woff += (i < w) ? wsum[i] : 0;
    if (gid < N_NODES) rowptr[gid] = v - orig + woff;
    if (threadIdx.x == 255) blocksum[blockIdx.x] = woff + v;
}

__global__ __launch_bounds__(512) void scan_blocksums_kernel(int* __restrict__ blocksum)
{
    __shared__ int s[512];
    int t = threadIdx.x;
    int orig = (t < SCAN_NB) ? blocksum[t] : 0;
    s[t] = orig;
    __syncthreads();
    for (int off = 1; off < 512; off <<= 1) {
        int u = (t >= off) ? s[t - off] : 0;
        __syncthreads();
        s[t] += u;
        __syncthreads();
    }
    if (t < SCAN_NB) blocksum[t] = s[t] - orig;
}

__global__ __launch_bounds__(256) void scan_add_kernel(
    int* __restrict__ rowptr, const int* __restrict__ blocksum)
{
    int gid = blockIdx.x * 256 + threadIdx.x;
    if (gid < N_NODES) rowptr[gid] += blocksum[blockIdx.x];
    if (gid == 0) rowptr[N_NODES] = N_EDGES;
}

// ---------------- CSR fill ----------------
__global__ __launch_bounds__(256) void csr_fill_kernel(
    const int* __restrict__ src, const int* __restrict__ dst,
    const int* __restrict__ rowptr, int* __restrict__ cursor, int* __restrict__ csr_src)
{
    int e = blockIdx.x * 256 + threadIdx.x;
    if (e < N_EDGES) {
        int d = dst[e];
        int slot = rowptr[d] + atomicAdd(&cursor[d], 1);
        csr_src[slot] = src[e];
    }
}

// ---------------- rsq_deg[n] = rsqrt(deg_out[n]) ----------------
__global__ __launch_bounds__(256) void deg_rsqrt_kernel(
    const int* __restrict__ deg_out, float* __restrict__ rsq)
{
    int n = blockIdx.x * 256 + threadIdx.x;
    if (n < N_NODES) rsq[n] = rsqrtf((float)deg_out[n]);
}

// =======================================================================
// Fused GAT layer, subgroup-parallel edges (unchanged).
// =======================================================================
template<int D>
__global__ __launch_bounds__(256) void gat_layer_kernel(
    const float* __restrict__ xw, const int* __restrict__ rowptr,
    const int* __restrict__ csr_src, const float* __restrict__ rsq_deg,
    float* __restrict__ h)
{
    constexpr int SG  = D / 8;
    constexpr int EPC = 64 / SG;
    int wid = blockIdx.x * 4 + (threadIdx.x >> 6);
    if (wid >= N_NODES) return;
    const int lane = threadIdx.x & 63;
    const int g = lane / SG;
    const int t = lane % SG;
    const int start = rowptr[wid], end = rowptr[wid + 1];

    const float* xdp = xw + (size_t)wid * D + 8 * t;
    float4 xd0 = *(const float4*)(xdp);
    float4 xd1 = *(const float4*)(xdp + 4);

    float m = -1e30f, l = 0.f;
    float acc[8];
#pragma unroll
    for (int c = 0; c < 8; c++) acc[c] = 0.f;

    for (int base = start; base < end; base += EPC) {
        int i = base + g;
        bool valid = (i < end);
        int s = valid ? csr_src[i] : 0;
        const float* row = xw + (size_t)s * D + 8 * t;
        float4 a0 = *(const float4*)(row);
        float4 a1 = *(const float4*)(row + 4);
        float p = a0.x * xd0.x + a0.y * xd0.y + a0.z * xd0.z + a0.w * xd0.w
                + a1.x * xd1.x + a1.y * xd1.y + a1.z * xd1.z + a1.w * xd1.w;
#pragma unroll
        for (int off = SG / 2; off > 0; off >>= 1) p += __shfl_xor(p, off, 64);
        float rsd = valid ? rsq_deg[s] : 1.f;
        float gate = 1.0f / (1.0f + __expf(-(p * rsd)));
        float sc = valid ? p * gate : -1e30f;
        float mnew = fmaxf(m, sc);
        float scale = __expf(m - mnew);
        float w = valid ? __expf(sc - mnew) : 0.f;
        l = l * scale + w;
        acc[0] = acc[0] * scale + w * a0.x;
        acc[1] = acc[1] * scale + w * a0.y;
        acc[2] = acc[2] * scale + w * a0.z;
        acc[3] = acc[3] * scale + w * a0.w;
        acc[4] = acc[4] * scale + w * a1.x;
        acc[5] = acc[5] * scale + w * a1.y;
        acc[6] = acc[6] * scale + w * a1.z;
        acc[7] = acc[7] * scale + w * a1.w;
        m = mnew;
    }

    // merge subgroup states
#pragma unroll
    for (int off = SG; off < 64; off <<= 1) {
        float mo = __shfl_xor(m, off, 64);
        float lo = __shfl_xor(l, off, 64);
        float mnew = fmaxf(m, mo);
        float s1 = __expf(m - mnew), s2 = __expf(mo - mnew);
        l = l * s1 + lo * s2;
#pragma unroll
        for (int c = 0; c < 8; c++) {
            float ao = __shfl_xor(acc[c], off, 64);
            acc[c] = acc[c] * s1 + ao * s2;
        }
        m = mnew;
    }

    float invl = 1.0f / (l + 1e-16f);
    float ss = 0.f;
#pragma unroll
    for (int c = 0; c < 8; c++) { acc[c] *= invl; ss += acc[c] * acc[c]; }
#pragma unroll
    for (int off = SG / 2; off > 0; off >>= 1) ss += __shfl_xor(ss, off, 64);
    float inv = 1.0f / fmaxf(sqrtf(ss), 1e-12f);

    if (g == 0) {
        float4 o0, o1;
        o0.x = leaky(acc[0] * inv); o0.y = leaky(acc[1] * inv);
        o0.z = leaky(acc[2] * inv); o0.w = leaky(acc[3] * inv);
        o1.x = leaky(acc[4] * inv); o1.y = leaky(acc[5] * inv);
        o1.z = leaky(acc[6] * inv); o1.w = leaky(acc[7] * inv);
        float* op = h + (size_t)wid * D + 8 * t;
        *(float4*)(op) = o0;
        *(float4*)(op + 4) = o1;
    }
}

extern "C" void kernel_launch(void* const* d_in, const int* in_sizes, int n_in,
                              void* d_out, int out_size, void* d_ws, size_t ws_size,
                              hipStream_t stream)
{
    const float* features = (const float*)d_in[0];
    const float* id_emb   = (const float*)d_in[1];
    const int*   ei       = (const int*)d_in[2];
    const float* pref     = (const float*)d_in[3];
    const float* mlp_w    = (const float*)d_in[4];
    const float* mlp_b    = (const float*)d_in[5];
    const float* conv1_w  = (const float*)d_in[6];
    const float* lin1_w   = (const float*)d_in[7];
    const float* lin1_b   = (const float*)d_in[8];
    const float* g1_w     = (const float*)d_in[9];
    const float* g1_b     = (const float*)d_in[10];
    const float* conv2_w  = (const float*)d_in[11];
    const float* lin2_w   = (const float*)d_in[12];
    const float* lin2_b   = (const float*)d_in[13];
    const float* g2_w     = (const float*)d_in[14];
    const float* g2_b     = (const float*)d_in[15];
    const int* src = ei;
    const int* dst = ei + N_EDGES;
    float* out = (float*)d_out;

    // workspace layout (~122 MB + 180 KB weights)
    float* x       = (float*)d_ws;                         // [80000,128]
    float* xw      = x   + (size_t)N_NODES * DLAT;         // [80000,128]
    float* gat     = xw  + (size_t)N_NODES * DLAT;         // [80000,128] holds h
    int*   deg_out = (int*)(gat + (size_t)N_NODES * DLAT); // [80000]
    int*   cnt     = deg_out + N_NODES;                    // [80000] count->cursor->rsq_deg
    int*   rowptr  = cnt + N_NODES;                        // [80001]
    int*   csr_src = rowptr + N_NODES + 1;                 // [1e6]
    int*   blocksum = csr_src + N_EDGES;                   // [SCAN_NB]
    float* rsq_deg = (float*)cnt;
    // mlp W hi/lo alias 'gat' (used only before gat is written)
    unsigned short* mlpWh = (unsigned short*)gat;          // [128][768]
    unsigned short* mlpWl = mlpWh + (size_t)FEAT_DIM * DLAT;
    // persistent small weight tables, 16B-aligned tail
    unsigned short* wbase = (unsigned short*)(
        (((uintptr_t)(blocksum + SCAN_NB)) + 15) & ~(uintptr_t)15);
    unsigned short* wc1h = wbase;            // 128*128
    unsigned short* wc1l = wc1h + 16384;
    unsigned short* wl1h = wc1l + 16384;     // 64*128
    unsigned short* wl1l = wl1h + 8192;
    unsigned short* wg1h = wl1l + 8192;      // 64*128
    unsigned short* wg1l = wg1h + 8192;
    unsigned short* wc2h = wg1l + 8192;      // 64*64
    unsigned short* wc2l = wc2h + 4096;
    unsigned short* wl2h = wc2l + 4096;      // 64*64
    unsigned short* wl2l = wl2h + 4096;
    unsigned short* wg2h = wl2l + 4096;      // 64*64
    unsigned short* wg2l = wg2h + 4096;

    // ---- weight prep (transpose + hi/lo split) ----
    wt_prep_g_kernel<FEAT_DIM, DLAT><<<384, 256, 0, stream>>>(mlp_w, mlpWh, mlpWl);
    wt_prep_g_kernel<DLAT, DLAT><<<64, 256, 0, stream>>>(conv1_w, wc1h, wc1l);
    wt_prep_g_kernel<DLAT, DID><<<32, 256, 0, stream>>>(lin1_w, wl1h, wl1l);
    wt_prep_g_kernel<DLAT, DID><<<32, 256, 0, stream>>>(g1_w, wg1h, wg1l);
    wt_prep_g_kernel<DID, DID><<<16, 256, 0, stream>>>(conv2_w, wc2h, wc2l);
    wt_prep_g_kernel<DID, DID><<<16, 256, 0, stream>>>(lin2_w, wl2h, wl2l);
    wt_prep_g_kernel<DID, DID><<<16, 256, 0, stream>>>(g2_w, wg2h, wg2l);

    // ---- CSR build (shared by both layers) ----
    hipMemsetAsync(deg_out, 0, N_NODES * sizeof(int), stream);
    hipMemsetAsync(cnt, 0, N_NODES * sizeof(int), stream);
    count_kernel<<<(N_EDGES + 255) / 256, 256, 0, stream>>>(src, dst, deg_out, cnt);
    scan_local_kernel<<<SCAN_NB, 256, 0, stream>>>(cnt, rowptr, blocksum);
    scan_blocksums_kernel<<<1, 512, 0, stream>>>(blocksum);
    scan_add_kernel<<<SCAN_NB, 256, 0, stream>>>(rowptr, blocksum);
    hipMemsetAsync(cnt, 0, N_NODES * sizeof(int), stream);
    csr_fill_kernel<<<(N_EDGES + 255) / 256, 256, 0, stream>>>(src, dst, rowptr, cnt, csr_src);
    deg_rsqrt_kernel<<<(N_NODES + 255) / 256, 256, 0, stream>>>(deg_out, rsq_deg);

    // ---- x = l2norm(concat(preference, tanh(features@mlp_w+b))) ----
    hipMemcpyAsync(x, pref, (size_t)NUM_USER * DLAT * sizeof(float),
                   hipMemcpyDeviceToDevice, stream);
    mlp_mfma_kernel<<<(NUM_ITEM + 63) / 64, 256, 0, stream>>>(
        features, mlpWh, mlpWl, mlp_b, x + (size_t)NUM_USER * DLAT);
    l2norm_rows_kernel<<<(N_NODES + 3) / 4, 256, 0, stream>>>(x);

    // ---- GAT layer 1 (D=128) ----
    conv_mfma_kernel<DLAT, DLAT><<<N_NODES / 64, 256, 0, stream>>>(
        x, DLAT, wc1h, wc1l, xw, DLAT);
    gat_layer_kernel<DLAT><<<(N_NODES + 3) / 4, 256, 0, stream>>>(
        xw, rowptr, csr_src, rsq_deg, gat);
    combine_mfma_kernel<DLAT><<<N_NODES / 64, 256, 0, stream>>>(
        gat, DLAT, x, DLAT, wg1h, wg1l, wl1h, wl1l, g1_b, lin1_b, id_emb, out, 0);

    // ---- GAT layer 2 (D=64); x1 lives in out[:, :64] ----
    conv_mfma_kernel<DID, DID><<<N_NODES / 64, 256, 0, stream>>>(
        out, 2 * DID, wc2h, wc2l, xw, DID);
    gat_layer_kernel<DID><<<(N_NODES + 3) / 4, 256, 0, stream>>>(
        xw, rowptr, csr_src, rsq_deg, gat);
    combine_mfma_kernel<DID><<<N_NODES / 64, 256, 0, stream>>>(
        gat, DID, out, 2 * DID, wg2h, wg2l, wl2h, wl2l, g2_b, lin2_b, id_emb, out, DID);
}

// Round 10
// 488.713 us; speedup vs baseline: 1.0596x; 1.0596x over previous
//
#include <hip/hip_runtime.h>
#include <hip/hip_bf16.h>
#include <math.h>

#define NUM_USER 50000
#define NUM_ITEM 30000
#define N_NODES  80000
#define N_EDGES  1000000
#define FEAT_DIM 768
#define DLAT 128
#define DID  64
#define NEG_SLOPE 0.01f

#define SCAN_NB ((N_NODES + 255) / 256)   // 313 blocks

__device__ __forceinline__ float leaky(float v) { return v >= 0.f ? v : NEG_SLOPE * v; }

__device__ __forceinline__ float wave_reduce_sum(float v) {
#pragma unroll
    for (int off = 32; off > 0; off >>= 1) v += __shfl_xor(v, off, 64);
    return v;
}

// f32 -> bf16 RNE and back
__device__ __forceinline__ unsigned short f2bf(float f) {
    unsigned int u = __float_as_uint(f);
    unsigned int r = u + 0x7fffu + ((u >> 16) & 1u);
    return (unsigned short)(r >> 16);
}
__device__ __forceinline__ float bf2f(unsigned short h) {
    return __uint_as_float(((unsigned int)h) << 16);
}

typedef __attribute__((ext_vector_type(8))) short short8v;
typedef __attribute__((ext_vector_type(4))) float f32x4;

// unpack 8 packed bf16 (int4) -> 8 f32
__device__ __forceinline__ void unpack8(int4 v, float* f) {
    unsigned int u;
    u = (unsigned int)v.x; f[0] = __uint_as_float(u << 16); f[1] = __uint_as_float(u & 0xFFFF0000u);
    u = (unsigned int)v.y; f[2] = __uint_as_float(u << 16); f[3] = __uint_as_float(u & 0xFFFF0000u);
    u = (unsigned int)v.z; f[4] = __uint_as_float(u << 16); f[5] = __uint_as_float(u & 0xFFFF0000u);
    u = (unsigned int)v.w; f[6] = __uint_as_float(u << 16); f[7] = __uint_as_float(u & 0xFFFF0000u);
}

// split 8 f32 into bf16 hi/lo packed int4s and store
__device__ __forceinline__ void split_store8(
    float4 a, float4 b, unsigned short* dh, unsigned short* dl)
{
    float v[8] = {a.x, a.y, a.z, a.w, b.x, b.y, b.z, b.w};
    unsigned int ph[4], pl[4];
#pragma unroll
    for (int i = 0; i < 4; i++) {
        unsigned short h0 = f2bf(v[2*i]),   l0 = f2bf(v[2*i]   - bf2f(h0));
        unsigned short h1 = f2bf(v[2*i+1]), l1 = f2bf(v[2*i+1] - bf2f(h1));
        ph[i] = (unsigned int)h0 | ((unsigned int)h1 << 16);
        pl[i] = (unsigned int)l0 | ((unsigned int)l1 << 16);
    }
    *(int4*)dh = make_int4((int)ph[0], (int)ph[1], (int)ph[2], (int)ph[3]);
    *(int4*)dl = make_int4((int)pl[0], (int)pl[1], (int)pl[2], (int)pl[3]);
}

// ---------------- merged weight prep: transpose + hi/lo split, 7 tables ----------------
__device__ __forceinline__ void prep_one(int id, const float* W, int KK, int NN,
                                         unsigned short* Wh, unsigned short* Wl)
{
    int n = id / KK, k = id - n * KK;
    float v = W[(size_t)k * NN + n];
    unsigned short h = f2bf(v);
    Wh[id] = h;
    Wl[id] = f2bf(v - bf2f(h));
}

__global__ __launch_bounds__(256) void wt_prep_all_kernel(
    const float* __restrict__ mlp_w, const float* __restrict__ c1,
    const float* __restrict__ l1, const float* __restrict__ g1,
    const float* __restrict__ c2, const float* __restrict__ l2,
    const float* __restrict__ g2,
    unsigned short* __restrict__ mlpWh, unsigned short* __restrict__ mlpWl,
    unsigned short* __restrict__ wc1h, unsigned short* __restrict__ wc1l,
    unsigned short* __restrict__ wl1h, unsigned short* __restrict__ wl1l,
    unsigned short* __restrict__ wg1h, unsigned short* __restrict__ wg1l,
    unsigned short* __restrict__ wc2h, unsigned short* __restrict__ wc2l,
    unsigned short* __restrict__ wl2h, unsigned short* __restrict__ wl2l,
    unsigned short* __restrict__ wg2h, unsigned short* __restrict__ wg2l)
{
    int id = blockIdx.x * 256 + threadIdx.x;
    if (id < 98304)       prep_one(id,          mlp_w, FEAT_DIM, DLAT, mlpWh, mlpWl);
    else if (id < 114688) prep_one(id - 98304,  c1, DLAT, DLAT, wc1h, wc1l);
    else if (id < 122880) prep_one(id - 114688, l1, DLAT, DID,  wl1h, wl1l);
    else if (id < 131072) prep_one(id - 122880, g1, DLAT, DID,  wg1h, wg1l);
    else if (id < 135168) prep_one(id - 131072, c2, DID,  DID,  wc2h, wc2l);
    else if (id < 139264) prep_one(id - 135168, l2, DID,  DID,  wl2h, wl2l);
    else if (id < 143360) prep_one(id - 139264, g2, DID,  DID,  wg2h, wg2l);
}

// =======================================================================
// conv via split-bf16 MFMA: O(bf16)[80000,NC] = X(f32) @ W[K,NC], NC==K.
// Block 64 rows, 4 waves. A staged f32->hi/lo LDS; B frags from global (L2-hot).
// =======================================================================
template<int K, int NC>
__global__ __launch_bounds__(256) void conv_mfma_kernel(
    const float* __restrict__ X, int ldx,
    const unsigned short* __restrict__ Wth, const unsigned short* __restrict__ Wtl,
    unsigned short* __restrict__ O, int ldo)
{
    constexpr int NW = NC / 64;
    constexpr int MW = 4 / NW;
    constexpr int WROWS = 64 / MW;
    constexpr int MF = WROWS / 16;
    constexpr int KSTEPS = K / 32;
    constexpr int KP = K + 8;

    __shared__ unsigned short sAh[64][KP];
    __shared__ unsigned short sAl[64][KP];

    const int tid = threadIdx.x;
    const int lane = tid & 63;
    const int w = tid >> 6;
    const int wr = w / NW, wc = w % NW;
    const int r0 = blockIdx.x * 64;

#pragma unroll
    for (int it = 0; it < K / 32; it++) {
        int slot = tid + it * 256;
        int row = slot / (K / 8);
        int k8 = (slot % (K / 8)) * 8;
        const float4* p = (const float4*)(X + (size_t)(r0 + row) * ldx + k8);
        split_store8(p[0], p[1], &sAh[row][k8], &sAl[row][k8]);
    }
    __syncthreads();

    f32x4 acc[MF][4];
#pragma unroll
    for (int m = 0; m < MF; m++)
#pragma unroll
        for (int n = 0; n < 4; n++) acc[m][n] = (f32x4){0.f, 0.f, 0.f, 0.f};

#pragma unroll
    for (int ks = 0; ks < KSTEPS; ks++) {
        int klane = ks * 32 + (lane >> 4) * 8;
        short8v ah[MF], al[MF];
#pragma unroll
        for (int m = 0; m < MF; m++) {
            int row = wr * WROWS + m * 16 + (lane & 15);
            ah[m] = *(const short8v*)&sAh[row][klane];
            al[m] = *(const short8v*)&sAl[row][klane];
        }
#pragma unroll
        for (int n = 0; n < 4; n++) {
            int col = wc * 64 + n * 16 + (lane & 15);
            short8v bh = *(const short8v*)(Wth + (size_t)col * K + klane);
            short8v bl = *(const short8v*)(Wtl + (size_t)col * K + klane);
#pragma unroll
            for (int m = 0; m < MF; m++) {
                acc[m][n] = __builtin_amdgcn_mfma_f32_16x16x32_bf16(ah[m], bh, acc[m][n], 0, 0, 0);
                acc[m][n] = __builtin_amdgcn_mfma_f32_16x16x32_bf16(ah[m], bl, acc[m][n], 0, 0, 0);
                acc[m][n] = __builtin_amdgcn_mfma_f32_16x16x32_bf16(al[m], bh, acc[m][n], 0, 0, 0);
            }
        }
    }

#pragma unroll
    for (int m = 0; m < MF; m++) {
        int rbase = r0 + wr * WROWS + m * 16 + (lane >> 4) * 4;
#pragma unroll
        for (int n = 0; n < 4; n++) {
            int col = wc * 64 + n * 16 + (lane & 15);
#pragma unroll
            for (int q = 0; q < 4; q++)
                O[(size_t)(rbase + q) * ldo + col] = f2bf(acc[m][n][q]);
        }
    }
}

// =======================================================================
// combine via split-bf16 MFMA (N=64):
// out[n][out_off+c] = leaky(H@G + g_b + leaky(X@L + lin_b) + id_emb)
// =======================================================================
template<int K>
__global__ __launch_bounds__(256) void combine_mfma_kernel(
    const float* __restrict__ H, int ldh,
    const float* __restrict__ X, int ldx,
    const unsigned short* __restrict__ Gth, const unsigned short* __restrict__ Gtl,
    const unsigned short* __restrict__ Lth, const unsigned short* __restrict__ Ltl,
    const float* __restrict__ g_b, const float* __restrict__ lin_b,
    const float* __restrict__ id_emb, float* __restrict__ out, int out_off)
{
    constexpr int KSTEPS = K / 32;
    constexpr int KP = K + 8;

    __shared__ unsigned short sHh[64][KP];
    __shared__ unsigned short sHl[64][KP];
    __shared__ unsigned short sXh[64][KP];
    __shared__ unsigned short sXl[64][KP];

    const int tid = threadIdx.x;
    const int lane = tid & 63;
    const int wr = tid >> 6;
    const int r0 = blockIdx.x * 64;

#pragma unroll
    for (int it = 0; it < K / 32; it++) {
        int slot = tid + it * 256;
        int row = slot / (K / 8);
        int k8 = (slot % (K / 8)) * 8;
        const float4* ph = (const float4*)(H + (size_t)(r0 + row) * ldh + k8);
        split_store8(ph[0], ph[1], &sHh[row][k8], &sHl[row][k8]);
        const float4* px = (const float4*)(X + (size_t)(r0 + row) * ldx + k8);
        split_store8(px[0], px[1], &sXh[row][k8], &sXl[row][k8]);
    }
    __syncthreads();

    f32x4 accG[4], accL[4];
#pragma unroll
    for (int n = 0; n < 4; n++) {
        accG[n] = (f32x4){0.f, 0.f, 0.f, 0.f};
        accL[n] = (f32x4){0.f, 0.f, 0.f, 0.f};
    }

#pragma unroll
    for (int ks = 0; ks < KSTEPS; ks++) {
        int klane = ks * 32 + (lane >> 4) * 8;
        int row = wr * 16 + (lane & 15);
        short8v hh = *(const short8v*)&sHh[row][klane];
        short8v hl = *(const short8v*)&sHl[row][klane];
        short8v xh = *(const short8v*)&sXh[row][klane];
        short8v xl = *(const short8v*)&sXl[row][klane];
#pragma unroll
        for (int n = 0; n < 4; n++) {
            int col = n * 16 + (lane & 15);
            short8v gh = *(const short8v*)(Gth + (size_t)col * K + klane);
            short8v gl = *(const short8v*)(Gtl + (size_t)col * K + klane);
            short8v lh = *(const short8v*)(Lth + (size_t)col * K + klane);
            short8v ll = *(const short8v*)(Ltl + (size_t)col * K + klane);
            accG[n] = __builtin_amdgcn_mfma_f32_16x16x32_bf16(hh, gh, accG[n], 0, 0, 0);
            accG[n] = __builtin_amdgcn_mfma_f32_16x16x32_bf16(hh, gl, accG[n], 0, 0, 0);
            accG[n] = __builtin_amdgcn_mfma_f32_16x16x32_bf16(hl, gh, accG[n], 0, 0, 0);
            accL[n] = __builtin_amdgcn_mfma_f32_16x16x32_bf16(xh, lh, accL[n], 0, 0, 0);
            accL[n] = __builtin_amdgcn_mfma_f32_16x16x32_bf16(xh, ll, accL[n], 0, 0, 0);
            accL[n] = __builtin_amdgcn_mfma_f32_16x16x32_bf16(xl, lh, accL[n], 0, 0, 0);
        }
    }

    int rbase = r0 + wr * 16 + (lane >> 4) * 4;
#pragma unroll
    for (int n = 0; n < 4; n++) {
        int col = n * 16 + (lane & 15);
        float gb = g_b[col], lb = lin_b[col];
#pragma unroll
        for (int q = 0; q < 4; q++) {
            int gr = rbase + q;
            float xhv = leaky(accL[n][q] + lb) + id_emb[(size_t)gr * DID + col];
            float v = leaky(accG[n][q] + gb + xhv);
            out[(size_t)gr * (2 * DID) + out_off + col] = v;
        }
    }
}

// =======================================================================
// MLP via split-bf16 MFMA: xout = tanh(F @ W + b), item rows (pre-offset).
// =======================================================================
__global__ __launch_bounds__(256) void mlp_mfma_kernel(
    const float* __restrict__ F,
    const unsigned short* __restrict__ Wh, const unsigned short* __restrict__ Wl,
    const float* __restrict__ bias, float* __restrict__ xout)
{
    __shared__ unsigned short sAh[64][72];
    __shared__ unsigned short sAl[64][72];
    __shared__ unsigned short sWh[128][72];
    __shared__ unsigned short sWlo[128][72];

    const int tid = threadIdx.x;
    const int lane = tid & 63;
    const int w = tid >> 6;
    const int wr = w >> 1, wc = w & 1;
    const int r0 = blockIdx.x * 64;

    f32x4 acc[2][4];
#pragma unroll
    for (int m = 0; m < 2; m++)
#pragma unroll
        for (int n = 0; n < 4; n++) acc[m][n] = (f32x4){0.f, 0.f, 0.f, 0.f};

    for (int kc = 0; kc < FEAT_DIM; kc += 64) {
#pragma unroll
        for (int it = 0; it < 2; it++) {
            int slot = tid + it * 256;
            int row = slot >> 3;
            int k8 = (slot & 7) * 8;
            int gr = r0 + row;
            float4 a = make_float4(0.f, 0.f, 0.f, 0.f), b = a;
            if (gr < NUM_ITEM) {
                const float4* p = (const float4*)(F + (size_t)gr * FEAT_DIM + kc + k8);
                a = p[0]; b = p[1];
            }
            split_store8(a, b, &sAh[row][k8], &sAl[row][k8]);
        }
#pragma unroll
        for (int it = 0; it < 4; it++) {
            int slot = tid + it * 256;
            int n = slot >> 3;
            int k8 = (slot & 7) * 8;
            *(int4*)&sWh[n][k8]  = *(const int4*)(Wh + (size_t)n * FEAT_DIM + kc + k8);
            *(int4*)&sWlo[n][k8] = *(const int4*)(Wl + (size_t)n * FEAT_DIM + kc + k8);
        }
        __syncthreads();

#pragma unroll
        for (int k0 = 0; k0 < 64; k0 += 32) {
            int klane = k0 + (lane >> 4) * 8;
            short8v ah[2], al[2], bh[4], bl[4];
#pragma unroll
            for (int m = 0; m < 2; m++) {
                int row = wr * 32 + m * 16 + (lane & 15);
                ah[m] = *(const short8v*)&sAh[row][klane];
                al[m] = *(const short8v*)&sAl[row][klane];
            }
#pragma unroll
            for (int n = 0; n < 4; n++) {
                int col = wc * 64 + n * 16 + (lane & 15);
                bh[n] = *(const short8v*)&sWh[col][klane];
                bl[n] = *(const short8v*)&sWlo[col][klane];
            }
#pragma unroll
            for (int m = 0; m < 2; m++)
#pragma unroll
                for (int n = 0; n < 4; n++) {
                    acc[m][n] = __builtin_amdgcn_mfma_f32_16x16x32_bf16(ah[m], bh[n], acc[m][n], 0, 0, 0);
                    acc[m][n] = __builtin_amdgcn_mfma_f32_16x16x32_bf16(ah[m], bl[n], acc[m][n], 0, 0, 0);
                    acc[m][n] = __builtin_amdgcn_mfma_f32_16x16x32_bf16(al[m], bh[n], acc[m][n], 0, 0, 0);
                }
        }
        __syncthreads();
    }

#pragma unroll
    for (int m = 0; m < 2; m++) {
        int rbase = r0 + wr * 32 + m * 16 + (lane >> 4) * 4;
#pragma unroll
        for (int n = 0; n < 4; n++) {
            int col = wc * 64 + n * 16 + (lane & 15);
            float bv = bias[col];
#pragma unroll
            for (int q = 0; q < 4; q++) {
                int gr = rbase + q;
                if (gr < NUM_ITEM)
                    xout[(size_t)gr * DLAT + col] = tanhf(acc[m][n][q] + bv);
            }
        }
    }
}

// ---------------- normcopy: x[n] = l2norm(n<NUM_USER ? pref[n] : x[n]) ----------------
__global__ __launch_bounds__(256) void normcopy_kernel(
    const float* __restrict__ pref, float* __restrict__ x)
{
    int wid = blockIdx.x * 4 + (threadIdx.x >> 6);
    if (wid >= N_NODES) return;
    int lane = threadIdx.x & 63;
    const float* srow = (wid < NUM_USER) ? (pref + (size_t)wid * DLAT)
                                         : (x + (size_t)wid * DLAT);
    float v0 = srow[lane], v1 = srow[lane + 64];
    float s = wave_reduce_sum(v0 * v0 + v1 * v1);
    float inv = 1.0f / fmaxf(sqrtf(s), 1e-12f);
    float* drow = x + (size_t)wid * DLAT;
    drow[lane] = v0 * inv;
    drow[lane + 64] = v1 * inv;
}

// ---------------- degree count ----------------
__global__ __launch_bounds__(256) void count_kernel(
    const int* __restrict__ src, const int* __restrict__ dst,
    int* __restrict__ deg_out, int* __restrict__ cnt_in)
{
    int e = blockIdx.x * 256 + threadIdx.x;
    if (e < N_EDGES) {
        atomicAdd(&deg_out[src[e]], 1);
        atomicAdd(&cnt_in[dst[e]], 1);
    }
}

// ---------------- 3-phase multi-block exclusive scan ----------------
__global__ __launch_bounds__(256) void scan_local_kernel(
    const int* __restrict__ cnt, int* __restrict__ rowptr, int* __restrict__ blocksum)
{
    __shared__ int wsum[4];
    int gid = blockIdx.x * 256 + threadIdx.x;
    int lane = threadIdx.x & 63, w = threadIdx.x >> 6;
    int orig = (gid < N_NODES) ? cnt[gid] : 0;
    int v = orig;
#pragma unroll
    for (int off = 1; off < 64; off <<= 1) {
        int u = __shfl_up(v, off, 64);
        if (lane >= off) v += u;
    }
    if (lane == 63) wsum[w] = v;
    __syncthreads();
    int woff = 0;
#pragma unroll
    for (int i = 0; i < 4; i++) woff += (i < w) ? wsum[i] : 0;
    if (gid < N_NODES) rowptr[gid] = v - orig + woff;
    if (threadIdx.x == 255) blocksum[blockIdx.x] = woff + v;
}

__global__ __launch_bounds__(512) void scan_blocksums_kernel(int* __restrict__ blocksum)
{
    __shared__ int s[512];
    int t = threadIdx.x;
    int orig = (t < SCAN_NB) ? blocksum[t] : 0;
    s[t] = orig;
    __syncthreads();
    for (int off = 1; off < 512; off <<= 1) {
        int u = (t >= off) ? s[t - off] : 0;
        __syncthreads();
        s[t] += u;
        __syncthreads();
    }
    if (t < SCAN_NB) blocksum[t] = s[t] - orig;
}

// scan_add + cnt rezero (cursor for csr_fill) + rsq_deg, fused
__global__ __launch_bounds__(256) void scan_add_plus_kernel(
    int* __restrict__ rowptr, const int* __restrict__ blocksum,
    int* __restrict__ cnt, const int* __restrict__ deg_out, float* __restrict__ rsq)
{
    int gid = blockIdx.x * 256 + threadIdx.x;
    if (gid < N_NODES) {
        rowptr[gid] += blocksum[blockIdx.x];
        cnt[gid] = 0;
        rsq[gid] = rsqrtf((float)deg_out[gid]);
    }
    if (gid == 0) rowptr[N_NODES] = N_EDGES;
}

// ---------------- CSR fill ----------------
__global__ __launch_bounds__(256) void csr_fill_kernel(
    const int* __restrict__ src, const int* __restrict__ dst,
    const int* __restrict__ rowptr, int* __restrict__ cursor, int* __restrict__ csr_src)
{
    int e = blockIdx.x * 256 + threadIdx.x;
    if (e < N_EDGES) {
        int d = dst[e];
        int slot = rowptr[d] + atomicAdd(&cursor[d], 1);
        csr_src[slot] = src[e];
    }
}

// =======================================================================
// Fused GAT layer, subgroup-parallel edges; xw is bf16-packed.
// =======================================================================
template<int D>
__global__ __launch_bounds__(256) void gat_layer_kernel(
    const unsigned short* __restrict__ xw, const int* __restrict__ rowptr,
    const int* __restrict__ csr_src, const float* __restrict__ rsq_deg,
    float* __restrict__ h)
{
    constexpr int SG  = D / 8;
    constexpr int EPC = 64 / SG;
    int wid = blockIdx.x * 4 + (threadIdx.x >> 6);
    if (wid >= N_NODES) return;
    const int lane = threadIdx.x & 63;
    const int g = lane / SG;
    const int t = lane % SG;
    const int start = rowptr[wid], end = rowptr[wid + 1];

    float xd[8];
    {
        int4 v = *(const int4*)(xw + (size_t)wid * D + 8 * t);
        unpack8(v, xd);
    }

    float m = -1e30f, l = 0.f;
    float acc[8];
#pragma unroll
    for (int c = 0; c < 8; c++) acc[c] = 0.f;

    for (int base = start; base < end; base += EPC) {
        int i = base + g;
        bool valid = (i < end);
        int s = valid ? csr_src[i] : 0;
        int4 av = *(const int4*)(xw + (size_t)s * D + 8 * t);
        float a[8];
        unpack8(av, a);
        float p = a[0]*xd[0] + a[1]*xd[1] + a[2]*xd[2] + a[3]*xd[3]
                + a[4]*xd[4] + a[5]*xd[5] + a[6]*xd[6] + a[7]*xd[7];
#pragma unroll
        for (int off = SG / 2; off > 0; off >>= 1) p += __shfl_xor(p, off, 64);
        float rsd = valid ? rsq_deg[s] : 1.f;
        float gate = 1.0f / (1.0f + __expf(-(p * rsd)));
        float sc = valid ? p * gate : -1e30f;
        float mnew = fmaxf(m, sc);
        float scale = __expf(m - mnew);
        float w = valid ? __expf(sc - mnew) : 0.f;
        l = l * scale + w;
#pragma unroll
        for (int c = 0; c < 8; c++) acc[c] = acc[c] * scale + w * a[c];
        m = mnew;
    }

    // merge subgroup states
#pragma unroll
    for (int off = SG; off < 64; off <<= 1) {
        float mo = __shfl_xor(m, off, 64);
        float lo = __shfl_xor(l, off, 64);
        float mnew = fmaxf(m, mo);
        float s1 = __expf(m - mnew), s2 = __expf(mo - mnew);
        l = l * s1 + lo * s2;
#pragma unroll
        for (int c = 0; c < 8; c++) {
            float ao = __shfl_xor(acc[c], off, 64);
            acc[c] = acc[c] * s1 + ao * s2;
        }
        m = mnew;
    }

    float invl = 1.0f / (l + 1e-16f);
    float ss = 0.f;
#pragma unroll
    for (int c = 0; c < 8; c++) { acc[c] *= invl; ss += acc[c] * acc[c]; }
#pragma unroll
    for (int off = SG / 2; off > 0; off >>= 1) ss += __shfl_xor(ss, off, 64);
    float inv = 1.0f / fmaxf(sqrtf(ss), 1e-12f);

    if (g == 0) {
        float4 o0, o1;
        o0.x = leaky(acc[0] * inv); o0.y = leaky(acc[1] * inv);
        o0.z = leaky(acc[2] * inv); o0.w = leaky(acc[3] * inv);
        o1.x = leaky(acc[4] * inv); o1.y = leaky(acc[5] * inv);
        o1.z = leaky(acc[6] * inv); o1.w = leaky(acc[7] * inv);
        float* op = h + (size_t)wid * D + 8 * t;
        *(float4*)(op) = o0;
        *(float4*)(op + 4) = o1;
    }
}

extern "C" void kernel_launch(void* const* d_in, const int* in_sizes, int n_in,
                              void* d_out, int out_size, void* d_ws, size_t ws_size,
                              hipStream_t stream)
{
    const float* features = (const float*)d_in[0];
    const float* id_emb   = (const float*)d_in[1];
    const int*   ei       = (const int*)d_in[2];
    const float* pref     = (const float*)d_in[3];
    const float* mlp_w    = (const float*)d_in[4];
    const float* mlp_b    = (const float*)d_in[5];
    const float* conv1_w  = (const float*)d_in[6];
    const float* lin1_w   = (const float*)d_in[7];
    const float* lin1_b   = (const float*)d_in[8];
    const float* g1_w     = (const float*)d_in[9];
    const float* g1_b     = (const float*)d_in[10];
    const float* conv2_w  = (const float*)d_in[11];
    const float* lin2_w   = (const float*)d_in[12];
    const float* lin2_b   = (const float*)d_in[13];
    const float* g2_w     = (const float*)d_in[14];
    const float* g2_b     = (const float*)d_in[15];
    const int* src = ei;
    const int* dst = ei + N_EDGES;
    float* out = (float*)d_out;

    // workspace layout (~108 MB)
    float* x        = (float*)d_ws;                            // [80000,128] f32
    unsigned short* xwb = (unsigned short*)(x + (size_t)N_NODES * DLAT);  // [80000,128] bf16
    float* gat      = (float*)(xwb + (size_t)N_NODES * DLAT);  // [80000,128] f32 (holds h)
    int*   deg_out  = (int*)(gat + (size_t)N_NODES * DLAT);    // [80000]
    int*   cnt      = deg_out + N_NODES;                       // [80000] count->cursor
    int*   rowptr   = cnt + N_NODES;                           // [80001]
    int*   csr_src  = rowptr + N_NODES + 1;                    // [1e6]
    int*   blocksum = csr_src + N_EDGES;                       // [SCAN_NB]
    float* rsq_deg  = (float*)(blocksum + SCAN_NB);            // [80000]
    // mlp W hi/lo alias 'gat' (used only before gat is written)
    unsigned short* mlpWh = (unsigned short*)gat;              // [128][768]
    unsigned short* mlpWl = mlpWh + (size_t)FEAT_DIM * DLAT;
    // persistent small weight tables, 16B-aligned tail
    unsigned short* wbase = (unsigned short*)(
        (((uintptr_t)(rsq_deg + N_NODES)) + 15) & ~(uintptr_t)15);
    unsigned short* wc1h = wbase;            // 128*128
    unsigned short* wc1l = wc1h + 16384;
    unsigned short* wl1h = wc1l + 16384;     // 64*128
    unsigned short* wl1l = wl1h + 8192;
    unsigned short* wg1h = wl1l + 8192;      // 64*128
    unsigned short* wg1l = wg1h + 8192;
    unsigned short* wc2h = wg1l + 8192;      // 64*64
    unsigned short* wc2l = wc2h + 4096;
    unsigned short* wl2h = wc2l + 4096;      // 64*64
    unsigned short* wl2l = wl2h + 4096;
    unsigned short* wg2h = wl2l + 4096;      // 64*64
    unsigned short* wg2l = wg2h + 4096;

    // ---- prep: weights (1 kernel), zero deg_out+cnt (adjacent, 1 memset) ----
    hipMemsetAsync(deg_out, 0, 2 * N_NODES * sizeof(int), stream);
    wt_prep_all_kernel<<<560, 256, 0, stream>>>(
        mlp_w, conv1_w, lin1_w, g1_w, conv2_w, lin2_w, g2_w,
        mlpWh, mlpWl, wc1h, wc1l, wl1h, wl1l, wg1h, wg1l,
        wc2h, wc2l, wl2h, wl2l, wg2h, wg2l);

    // ---- CSR build ----
    count_kernel<<<(N_EDGES + 255) / 256, 256, 0, stream>>>(src, dst, deg_out, cnt);
    scan_local_kernel<<<SCAN_NB, 256, 0, stream>>>(cnt, rowptr, blocksum);
    scan_blocksums_kernel<<<1, 512, 0, stream>>>(blocksum);
    scan_add_plus_kernel<<<SCAN_NB, 256, 0, stream>>>(rowptr, blocksum, cnt, deg_out, rsq_deg);
    csr_fill_kernel<<<(N_EDGES + 255) / 256, 256, 0, stream>>>(src, dst, rowptr, cnt, csr_src);

    // ---- x = l2norm(concat(preference, tanh(features@mlp_w+b))) ----
    mlp_mfma_kernel<<<(NUM_ITEM + 63) / 64, 256, 0, stream>>>(
        features, mlpWh, mlpWl, mlp_b, x + (size_t)NUM_USER * DLAT);
    normcopy_kernel<<<(N_NODES + 3) / 4, 256, 0, stream>>>(pref, x);

    // ---- GAT layer 1 (D=128) ----
    conv_mfma_kernel<DLAT, DLAT><<<N_NODES / 64, 256, 0, stream>>>(
        x, DLAT, wc1h, wc1l, xwb, DLAT);
    gat_layer_kernel<DLAT><<<(N_NODES + 3) / 4, 256, 0, stream>>>(
        xwb, rowptr, csr_src, rsq_deg, gat);
    combine_mfma_kernel<DLAT><<<N_NODES / 64, 256, 0, stream>>>(
        gat, DLAT, x, DLAT, wg1h, wg1l, wl1h, wl1l, g1_b, lin1_b, id_emb, out, 0);

    // ---- GAT layer 2 (D=64); x1 lives in out[:, :64] ----
    conv_mfma_kernel<DID, DID><<<N_NODES / 64, 256, 0, stream>>>(
        out, 2 * DID, wc2h, wc2l, xwb, DID);
    gat_layer_kernel<DID><<<(N_NODES + 3) / 4, 256, 0, stream>>>(
        xwb, rowptr, csr_src, rsq_deg, gat);
    combine_mfma_kernel<DID><<<N_NODES / 64, 256, 0, stream>>>(
        gat, DID, out, 2 * DID, wg2h, wg2l, wl2h, wl2l, g2_b, lin2_b, id_emb, out, DID);
}

// Round 11
// 452.702 us; speedup vs baseline: 1.1439x; 1.0795x over previous
//
#include <hip/hip_runtime.h>
#include <hip/hip_bf16.h>
#include <math.h>

#define NUM_USER 50000
#define NUM_ITEM 30000
#define N_NODES  80000
#define N_EDGES  1000000
#define FEAT_DIM 768
#define DLAT 128
#define DID  64
#define NEG_SLOPE 0.01f

#define SCAN_NB ((N_NODES + 255) / 256)       // 313
#define NB_COUNT ((N_EDGES + 255) / 256)      // 3907
#define NB_WT 560                              // 143360 / 256
#define NB_MLP ((NUM_ITEM + 63) / 64)          // 469
#define NB_NORM (N_NODES / 8)                  // 10000 (512-thr blocks, 8 rows each)
#define NB_CONV1 (N_NODES / 64)                // 1250

__device__ __forceinline__ float leaky(float v) { return v >= 0.f ? v : NEG_SLOPE * v; }

__device__ __forceinline__ float wave_reduce_sum(float v) {
#pragma unroll
    for (int off = 32; off > 0; off >>= 1) v += __shfl_xor(v, off, 64);
    return v;
}

__device__ __forceinline__ unsigned short f2bf(float f) {
    unsigned int u = __float_as_uint(f);
    unsigned int r = u + 0x7fffu + ((u >> 16) & 1u);
    return (unsigned short)(r >> 16);
}
__device__ __forceinline__ float bf2f(unsigned short h) {
    return __uint_as_float(((unsigned int)h) << 16);
}

typedef __attribute__((ext_vector_type(8))) short short8v;
typedef __attribute__((ext_vector_type(4))) float f32x4;

__device__ __forceinline__ void unpack8(int4 v, float* f) {
    unsigned int u;
    u = (unsigned int)v.x; f[0] = __uint_as_float(u << 16); f[1] = __uint_as_float(u & 0xFFFF0000u);
    u = (unsigned int)v.y; f[2] = __uint_as_float(u << 16); f[3] = __uint_as_float(u & 0xFFFF0000u);
    u = (unsigned int)v.z; f[4] = __uint_as_float(u << 16); f[5] = __uint_as_float(u & 0xFFFF0000u);
    u = (unsigned int)v.w; f[6] = __uint_as_float(u << 16); f[7] = __uint_as_float(u & 0xFFFF0000u);
}

__device__ __forceinline__ void split_store8(
    float4 a, float4 b, unsigned short* dh, unsigned short* dl)
{
    float v[8] = {a.x, a.y, a.z, a.w, b.x, b.y, b.z, b.w};
    unsigned int ph[4], pl[4];
#pragma unroll
    for (int i = 0; i < 4; i++) {
        unsigned short h0 = f2bf(v[2*i]),   l0 = f2bf(v[2*i]   - bf2f(h0));
        unsigned short h1 = f2bf(v[2*i+1]), l1 = f2bf(v[2*i+1] - bf2f(h1));
        ph[i] = (unsigned int)h0 | ((unsigned int)h1 << 16);
        pl[i] = (unsigned int)l0 | ((unsigned int)l1 << 16);
    }
    *(int4*)dh = make_int4((int)ph[0], (int)ph[1], (int)ph[2], (int)ph[3]);
    *(int4*)dl = make_int4((int)pl[0], (int)pl[1], (int)pl[2], (int)pl[3]);
}

// ================= device bodies (parameterized by logical block id) =================

__device__ __forceinline__ void prep_one(int id, const float* W, int KK, int NN,
                                         unsigned short* Wh, unsigned short* Wl)
{
    int n = id / KK, k = id - n * KK;
    float v = W[(size_t)k * NN + n];
    unsigned short h = f2bf(v);
    Wh[id] = h;
    Wl[id] = f2bf(v - bf2f(h));
}

__device__ void wt_prep_body(int pb,
    const float* mlp_w, const float* c1, const float* l1, const float* g1,
    const float* c2, const float* l2, const float* g2,
    unsigned short* mlpWh, unsigned short* mlpWl,
    unsigned short* wc1h, unsigned short* wc1l,
    unsigned short* wl1h, unsigned short* wl1l,
    unsigned short* wg1h, unsigned short* wg1l,
    unsigned short* wc2h, unsigned short* wc2l,
    unsigned short* wl2h, unsigned short* wl2l,
    unsigned short* wg2h, unsigned short* wg2l)
{
    int id = pb * 256 + threadIdx.x;
    if (id < 98304)       prep_one(id,          mlp_w, FEAT_DIM, DLAT, mlpWh, mlpWl);
    else if (id < 114688) prep_one(id - 98304,  c1, DLAT, DLAT, wc1h, wc1l);
    else if (id < 122880) prep_one(id - 114688, l1, DLAT, DID,  wl1h, wl1l);
    else if (id < 131072) prep_one(id - 122880, g1, DLAT, DID,  wg1h, wg1l);
    else if (id < 135168) prep_one(id - 131072, c2, DID,  DID,  wc2h, wc2l);
    else if (id < 139264) prep_one(id - 135168, l2, DID,  DID,  wl2h, wl2l);
    else if (id < 143360) prep_one(id - 139264, g2, DID,  DID,  wg2h, wg2l);
}

__device__ void count_body(int pb, const int* src, const int* dst,
                           int* deg_out, int* cnt_in)
{
    int e = pb * 256 + threadIdx.x;
    if (e < N_EDGES) {
        atomicAdd(&deg_out[src[e]], 1);
        atomicAdd(&cnt_in[dst[e]], 1);
    }
}

__device__ void scan_local_body(int pb, const int* cnt, int* rowptr, int* blocksum)
{
    __shared__ int wsum[4];
    int gid = pb * 256 + threadIdx.x;
    int lane = threadIdx.x & 63, w = threadIdx.x >> 6;
    int orig = (gid < N_NODES) ? cnt[gid] : 0;
    int v = orig;
#pragma unroll
    for (int off = 1; off < 64; off <<= 1) {
        int u = __shfl_up(v, off, 64);
        if (lane >= off) v += u;
    }
    if (lane == 63) wsum[w] = v;
    __syncthreads();
    int woff = 0;
#pragma unroll
    for (int i = 0; i < 4; i++) woff += (i < w) ? wsum[i] : 0;
    if (gid < N_NODES) rowptr[gid] = v - orig + woff;
    if (threadIdx.x == 255) blocksum[pb] = woff + v;
}

__device__ void scan_blocksums_body(int* blocksum)   // 512 threads
{
    __shared__ int s[512];
    int t = threadIdx.x;
    int orig = (t < SCAN_NB) ? blocksum[t] : 0;
    s[t] = orig;
    __syncthreads();
    for (int off = 1; off < 512; off <<= 1) {
        int u = (t >= off) ? s[t - off] : 0;
        __syncthreads();
        s[t] += u;
        __syncthreads();
    }
    if (t < SCAN_NB) blocksum[t] = s[t] - orig;
}

__device__ void scan_add_plus_body(int pb, int* rowptr, const int* blocksum,
                                   int* cnt, const int* deg_out, float* rsq)
{
    int gid = pb * 256 + threadIdx.x;
    if (gid < N_NODES) {
        rowptr[gid] += blocksum[pb];
        cnt[gid] = 0;
        rsq[gid] = rsqrtf((float)deg_out[gid]);
    }
    if (gid == 0) rowptr[N_NODES] = N_EDGES;
}

__device__ void mlp_body(int pb, const float* F,
    const unsigned short* Wh, const unsigned short* Wl,
    const float* bias, float* xout)
{
    __shared__ unsigned short sAh[64][72];
    __shared__ unsigned short sAl[64][72];
    __shared__ unsigned short sWh[128][72];
    __shared__ unsigned short sWlo[128][72];

    const int tid = threadIdx.x;
    const int lane = tid & 63;
    const int w = tid >> 6;
    const int wr = w >> 1, wc = w & 1;
    const int r0 = pb * 64;

    f32x4 acc[2][4];
#pragma unroll
    for (int m = 0; m < 2; m++)
#pragma unroll
        for (int n = 0; n < 4; n++) acc[m][n] = (f32x4){0.f, 0.f, 0.f, 0.f};

    for (int kc = 0; kc < FEAT_DIM; kc += 64) {
#pragma unroll
        for (int it = 0; it < 2; it++) {
            int slot = tid + it * 256;
            int row = slot >> 3;
            int k8 = (slot & 7) * 8;
            int gr = r0 + row;
            float4 a = make_float4(0.f, 0.f, 0.f, 0.f), b = a;
            if (gr < NUM_ITEM) {
                const float4* p = (const float4*)(F + (size_t)gr * FEAT_DIM + kc + k8);
                a = p[0]; b = p[1];
            }
            split_store8(a, b, &sAh[row][k8], &sAl[row][k8]);
        }
#pragma unroll
        for (int it = 0; it < 4; it++) {
            int slot = tid + it * 256;
            int n = slot >> 3;
            int k8 = (slot & 7) * 8;
            *(int4*)&sWh[n][k8]  = *(const int4*)(Wh + (size_t)n * FEAT_DIM + kc + k8);
            *(int4*)&sWlo[n][k8] = *(const int4*)(Wl + (size_t)n * FEAT_DIM + kc + k8);
        }
        __syncthreads();

#pragma unroll
        for (int k0 = 0; k0 < 64; k0 += 32) {
            int klane = k0 + (lane >> 4) * 8;
            short8v ah[2], al[2], bh[4], bl[4];
#pragma unroll
            for (int m = 0; m < 2; m++) {
                int row = wr * 32 + m * 16 + (lane & 15);
                ah[m] = *(const short8v*)&sAh[row][klane];
                al[m] = *(const short8v*)&sAl[row][klane];
            }
#pragma unroll
            for (int n = 0; n < 4; n++) {
                int col = wc * 64 + n * 16 + (lane & 15);
                bh[n] = *(const short8v*)&sWh[col][klane];
                bl[n] = *(const short8v*)&sWlo[col][klane];
            }
#pragma unroll
            for (int m = 0; m < 2; m++)
#pragma unroll
                for (int n = 0; n < 4; n++) {
                    acc[m][n] = __builtin_amdgcn_mfma_f32_16x16x32_bf16(ah[m], bh[n], acc[m][n], 0, 0, 0);
                    acc[m][n] = __builtin_amdgcn_mfma_f32_16x16x32_bf16(ah[m], bl[n], acc[m][n], 0, 0, 0);
                    acc[m][n] = __builtin_amdgcn_mfma_f32_16x16x32_bf16(al[m], bh[n], acc[m][n], 0, 0, 0);
                }
        }
        __syncthreads();
    }

#pragma unroll
    for (int m = 0; m < 2; m++) {
        int rbase = r0 + wr * 32 + m * 16 + (lane >> 4) * 4;
#pragma unroll
        for (int n = 0; n < 4; n++) {
            int col = wc * 64 + n * 16 + (lane & 15);
            float bv = bias[col];
#pragma unroll
            for (int q = 0; q < 4; q++) {
                int gr = rbase + q;
                if (gr < NUM_ITEM)
                    xout[(size_t)gr * DLAT + col] = tanhf(acc[m][n][q] + bv);
            }
        }
    }
}

// normcopy for 512-thread blocks: 8 rows per block
__device__ void normcopy_body(int pb, const float* pref, float* x)
{
    int wid = pb * 8 + (threadIdx.x >> 6);
    if (wid >= N_NODES) return;
    int lane = threadIdx.x & 63;
    const float* srow = (wid < NUM_USER) ? (pref + (size_t)wid * DLAT)
                                         : (x + (size_t)wid * DLAT);
    float v0 = srow[lane], v1 = srow[lane + 64];
    float s = wave_reduce_sum(v0 * v0 + v1 * v1);
    float inv = 1.0f / fmaxf(sqrtf(s), 1e-12f);
    float* drow = x + (size_t)wid * DLAT;
    drow[lane] = v0 * inv;
    drow[lane + 64] = v1 * inv;
}

template<int K, int NC>
__device__ void conv_body(int pb, const float* X, int ldx,
    const unsigned short* Wth, const unsigned short* Wtl,
    unsigned short* O, int ldo)
{
    constexpr int NW = NC / 64;
    constexpr int MW = 4 / NW;
    constexpr int WROWS = 64 / MW;
    constexpr int MF = WROWS / 16;
    constexpr int KSTEPS = K / 32;
    constexpr int KP = K + 8;

    __shared__ unsigned short sAh[64][KP];
    __shared__ unsigned short sAl[64][KP];

    const int tid = threadIdx.x;
    const int lane = tid & 63;
    const int w = tid >> 6;
    const int wr = w / NW, wc = w % NW;
    const int r0 = pb * 64;

#pragma unroll
    for (int it = 0; it < K / 32; it++) {
        int slot = tid + it * 256;
        int row = slot / (K / 8);
        int k8 = (slot % (K / 8)) * 8;
        const float4* p = (const float4*)(X + (size_t)(r0 + row) * ldx + k8);
        split_store8(p[0], p[1], &sAh[row][k8], &sAl[row][k8]);
    }
    __syncthreads();

    f32x4 acc[MF][4];
#pragma unroll
    for (int m = 0; m < MF; m++)
#pragma unroll
        for (int n = 0; n < 4; n++) acc[m][n] = (f32x4){0.f, 0.f, 0.f, 0.f};

#pragma unroll
    for (int ks = 0; ks < KSTEPS; ks++) {
        int klane = ks * 32 + (lane >> 4) * 8;
        short8v ah[MF], al[MF];
#pragma unroll
        for (int m = 0; m < MF; m++) {
            int row = wr * WROWS + m * 16 + (lane & 15);
            ah[m] = *(const short8v*)&sAh[row][klane];
            al[m] = *(const short8v*)&sAl[row][klane];
        }
#pragma unroll
        for (int n = 0; n < 4; n++) {
            int col = wc * 64 + n * 16 + (lane & 15);
            short8v bh = *(const short8v*)(Wth + (size_t)col * K + klane);
            short8v bl = *(const short8v*)(Wtl + (size_t)col * K + klane);
#pragma unroll
            for (int m = 0; m < MF; m++) {
                acc[m][n] = __builtin_amdgcn_mfma_f32_16x16x32_bf16(ah[m], bh, acc[m][n], 0, 0, 0);
                acc[m][n] = __builtin_amdgcn_mfma_f32_16x16x32_bf16(ah[m], bl, acc[m][n], 0, 0, 0);
                acc[m][n] = __builtin_amdgcn_mfma_f32_16x16x32_bf16(al[m], bh, acc[m][n], 0, 0, 0);
            }
        }
    }

#pragma unroll
    for (int m = 0; m < MF; m++) {
        int rbase = r0 + wr * WROWS + m * 16 + (lane >> 4) * 4;
#pragma unroll
        for (int n = 0; n < 4; n++) {
            int col = wc * 64 + n * 16 + (lane & 15);
#pragma unroll
            for (int q = 0; q < 4; q++)
                O[(size_t)(rbase + q) * ldo + col] = f2bf(acc[m][n][q]);
        }
    }
}

// ================= fused dispatch kernels =================

__global__ __launch_bounds__(256) void k_count_wtprep(
    const int* __restrict__ src, const int* __restrict__ dst,
    int* __restrict__ deg_out, int* __restrict__ cnt_in,
    const float* __restrict__ mlp_w, const float* __restrict__ c1,
    const float* __restrict__ l1, const float* __restrict__ g1,
    const float* __restrict__ c2, const float* __restrict__ l2,
    const float* __restrict__ g2,
    unsigned short* __restrict__ mlpWh, unsigned short* __restrict__ mlpWl,
    unsigned short* __restrict__ wc1h, unsigned short* __restrict__ wc1l,
    unsigned short* __restrict__ wl1h, unsigned short* __restrict__ wl1l,
    unsigned short* __restrict__ wg1h, unsigned short* __restrict__ wg1l,
    unsigned short* __restrict__ wc2h, unsigned short* __restrict__ wc2l,
    unsigned short* __restrict__ wl2h, unsigned short* __restrict__ wl2l,
    unsigned short* __restrict__ wg2h, unsigned short* __restrict__ wg2l)
{
    int b = blockIdx.x;
    if (b < NB_COUNT) count_body(b, src, dst, deg_out, cnt_in);
    else wt_prep_body(b - NB_COUNT, mlp_w, c1, l1, g1, c2, l2, g2,
                      mlpWh, mlpWl, wc1h, wc1l, wl1h, wl1l, wg1h, wg1l,
                      wc2h, wc2l, wl2h, wl2l, wg2h, wg2l);
}

__global__ __launch_bounds__(256) void k_scanl_mlp(
    const int* __restrict__ cnt, int* __restrict__ rowptr, int* __restrict__ blocksum,
    const float* __restrict__ F, const unsigned short* __restrict__ Wh,
    const unsigned short* __restrict__ Wl, const float* __restrict__ bias,
    float* __restrict__ xout)
{
    int b = blockIdx.x;
    if (b < SCAN_NB) scan_local_body(b, cnt, rowptr, blocksum);
    else mlp_body(b - SCAN_NB, F, Wh, Wl, bias, xout);
}

__global__ __launch_bounds__(512) void k_scanb_norm(
    int* __restrict__ blocksum, const float* __restrict__ pref, float* __restrict__ x)
{
    int b = blockIdx.x;
    if (b == 0) scan_blocksums_body(blocksum);
    else normcopy_body(b - 1, pref, x);
}

__global__ __launch_bounds__(256) void k_scana_conv1(
    int* __restrict__ rowptr, const int* __restrict__ blocksum,
    int* __restrict__ cnt, const int* __restrict__ deg_out, float* __restrict__ rsq,
    const float* __restrict__ X,
    const unsigned short* __restrict__ Wth, const unsigned short* __restrict__ Wtl,
    unsigned short* __restrict__ O)
{
    int b = blockIdx.x;
    if (b < SCAN_NB) scan_add_plus_body(b, rowptr, blocksum, cnt, deg_out, rsq);
    else conv_body<DLAT, DLAT>(b - SCAN_NB, X, DLAT, Wth, Wtl, O, DLAT);
}

// ================= standalone kernels =================

__global__ __launch_bounds__(256) void csr_fill_kernel(
    const int* __restrict__ src, const int* __restrict__ dst,
    const int* __restrict__ rowptr, int* __restrict__ cursor, int* __restrict__ csr_src)
{
    int e = blockIdx.x * 256 + threadIdx.x;
    if (e < N_EDGES) {
        int d = dst[e];
        int slot = rowptr[d] + atomicAdd(&cursor[d], 1);
        csr_src[slot] = src[e];
    }
}

__global__ __launch_bounds__(256) void conv2_kernel(
    const float* __restrict__ X, int ldx,
    const unsigned short* __restrict__ Wth, const unsigned short* __restrict__ Wtl,
    unsigned short* __restrict__ O, int ldo)
{
    conv_body<DID, DID>(blockIdx.x, X, ldx, Wth, Wtl, O, ldo);
}

// ---- gat layer: max-free softmax (shift-invariant; scores bounded, clamp 80) ----
template<int D>
__global__ __launch_bounds__(256) void gat_layer_kernel(
    const unsigned short* __restrict__ xw, const int* __restrict__ rowptr,
    const int* __restrict__ csr_src, const float* __restrict__ rsq_deg,
    float* __restrict__ h)
{
    constexpr int SG  = D / 8;
    constexpr int EPC = 64 / SG;
    int wid = blockIdx.x * 4 + (threadIdx.x >> 6);
    if (wid >= N_NODES) return;
    const int lane = threadIdx.x & 63;
    const int g = lane / SG;
    const int t = lane % SG;
    const int start = rowptr[wid], end = rowptr[wid + 1];

    float xd[8];
    unpack8(*(const int4*)(xw + (size_t)wid * D + 8 * t), xd);

    float l = 0.f;
    float acc[8];
#pragma unroll
    for (int c = 0; c < 8; c++) acc[c] = 0.f;

    for (int base = start; base < end; base += EPC) {
        int i = base + g;
        bool valid = (i < end);
        int s = valid ? csr_src[i] : 0;
        float a[8];
        unpack8(*(const int4*)(xw + (size_t)s * D + 8 * t), a);
        float p = a[0]*xd[0] + a[1]*xd[1] + a[2]*xd[2] + a[3]*xd[3]
                + a[4]*xd[4] + a[5]*xd[5] + a[6]*xd[6] + a[7]*xd[7];
#pragma unroll
        for (int off = SG / 2; off > 0; off >>= 1) p += __shfl_xor(p, off, 64);
        float rsd = valid ? rsq_deg[s] : 1.f;
        float gate = 1.0f / (1.0f + __expf(-(p * rsd)));
        float sc = fminf(p * gate, 80.f);
        float w = valid ? __expf(sc) : 0.f;
        l += w;
#pragma unroll
        for (int c = 0; c < 8; c++) acc[c] += w * a[c];
    }

    // merge subgroup partial sums (plain butterfly sums)
#pragma unroll
    for (int off = SG; off < 64; off <<= 1) {
        l += __shfl_xor(l, off, 64);
#pragma unroll
        for (int c = 0; c < 8; c++) acc[c] += __shfl_xor(acc[c], off, 64);
    }

    float invl = 1.0f / (l + 1e-16f);
    float ss = 0.f;
#pragma unroll
    for (int c = 0; c < 8; c++) { acc[c] *= invl; ss += acc[c] * acc[c]; }
#pragma unroll
    for (int off = SG / 2; off > 0; off >>= 1) ss += __shfl_xor(ss, off, 64);
    float inv = 1.0f / fmaxf(sqrtf(ss), 1e-12f);

    if (g == 0) {
        float4 o0, o1;
        o0.x = leaky(acc[0] * inv); o0.y = leaky(acc[1] * inv);
        o0.z = leaky(acc[2] * inv); o0.w = leaky(acc[3] * inv);
        o1.x = leaky(acc[4] * inv); o1.y = leaky(acc[5] * inv);
        o1.z = leaky(acc[6] * inv); o1.w = leaky(acc[7] * inv);
        float* op = h + (size_t)wid * D + 8 * t;
        *(float4*)(op) = o0;
        *(float4*)(op + 4) = o1;
    }
}

// ---- combine (unchanged) ----
template<int K>
__global__ __launch_bounds__(256) void combine_mfma_kernel(
    const float* __restrict__ H, int ldh,
    const float* __restrict__ X, int ldx,
    const unsigned short* __restrict__ Gth, const unsigned short* __restrict__ Gtl,
    const unsigned short* __restrict__ Lth, const unsigned short* __restrict__ Ltl,
    const float* __restrict__ g_b, const float* __restrict__ lin_b,
    const float* __restrict__ id_emb, float* __restrict__ out, int out_off)
{
    constexpr int KSTEPS = K / 32;
    constexpr int KP = K + 8;

    __shared__ unsigned short sHh[64][KP];
    __shared__ unsigned short sHl[64][KP];
    __shared__ unsigned short sXh[64][KP];
    __shared__ unsigned short sXl[64][KP];

    const int tid = threadIdx.x;
    const int lane = tid & 63;
    const int wr = tid >> 6;
    const int r0 = blockIdx.x * 64;

#pragma unroll
    for (int it = 0; it < K / 32; it++) {
        int slot = tid + it * 256;
        int row = slot / (K / 8);
        int k8 = (slot % (K / 8)) * 8;
        const float4* ph = (const float4*)(H + (size_t)(r0 + row) * ldh + k8);
        split_store8(ph[0], ph[1], &sHh[row][k8], &sHl[row][k8]);
        const float4* px = (const float4*)(X + (size_t)(r0 + row) * ldx + k8);
        split_store8(px[0], px[1], &sXh[row][k8], &sXl[row][k8]);
    }
    __syncthreads();

    f32x4 accG[4], accL[4];
#pragma unroll
    for (int n = 0; n < 4; n++) {
        accG[n] = (f32x4){0.f, 0.f, 0.f, 0.f};
        accL[n] = (f32x4){0.f, 0.f, 0.f, 0.f};
    }

#pragma unroll
    for (int ks = 0; ks < KSTEPS; ks++) {
        int klane = ks * 32 + (lane >> 4) * 8;
        int row = wr * 16 + (lane & 15);
        short8v hh = *(const short8v*)&sHh[row][klane];
        short8v hl = *(const short8v*)&sHl[row][klane];
        short8v xh = *(const short8v*)&sXh[row][klane];
        short8v xl = *(const short8v*)&sXl[row][klane];
#pragma unroll
        for (int n = 0; n < 4; n++) {
            int col = n * 16 + (lane & 15);
            short8v gh = *(const short8v*)(Gth + (size_t)col * K + klane);
            short8v gl = *(const short8v*)(Gtl + (size_t)col * K + klane);
            short8v lh = *(const short8v*)(Lth + (size_t)col * K + klane);
            short8v ll = *(const short8v*)(Ltl + (size_t)col * K + klane);
            accG[n] = __builtin_amdgcn_mfma_f32_16x16x32_bf16(hh, gh, accG[n], 0, 0, 0);
            accG[n] = __builtin_amdgcn_mfma_f32_16x16x32_bf16(hh, gl, accG[n], 0, 0, 0);
            accG[n] = __builtin_amdgcn_mfma_f32_16x16x32_bf16(hl, gh, accG[n], 0, 0, 0);
            accL[n] = __builtin_amdgcn_mfma_f32_16x16x32_bf16(xh, lh, accL[n], 0, 0, 0);
            accL[n] = __builtin_amdgcn_mfma_f32_16x16x32_bf16(xh, ll, accL[n], 0, 0, 0);
            accL[n] = __builtin_amdgcn_mfma_f32_16x16x32_bf16(xl, lh, accL[n], 0, 0, 0);
        }
    }

    int rbase = r0 + wr * 16 + (lane >> 4) * 4;
#pragma unroll
    for (int n = 0; n < 4; n++) {
        int col = n * 16 + (lane & 15);
        float gb = g_b[col], lb = lin_b[col];
#pragma unroll
        for (int q = 0; q < 4; q++) {
            int gr = rbase + q;
            float xhv = leaky(accL[n][q] + lb) + id_emb[(size_t)gr * DID + col];
            float v = leaky(accG[n][q] + gb + xhv);
            out[(size_t)gr * (2 * DID) + out_off + col] = v;
        }
    }
}

extern "C" void kernel_launch(void* const* d_in, const int* in_sizes, int n_in,
                              void* d_out, int out_size, void* d_ws, size_t ws_size,
                              hipStream_t stream)
{
    const float* features = (const float*)d_in[0];
    const float* id_emb   = (const float*)d_in[1];
    const int*   ei       = (const int*)d_in[2];
    const float* pref     = (const float*)d_in[3];
    const float* mlp_w    = (const float*)d_in[4];
    const float* mlp_b    = (const float*)d_in[5];
    const float* conv1_w  = (const float*)d_in[6];
    const float* lin1_w   = (const float*)d_in[7];
    const float* lin1_b   = (const float*)d_in[8];
    const float* g1_w     = (const float*)d_in[9];
    const float* g1_b     = (const float*)d_in[10];
    const float* conv2_w  = (const float*)d_in[11];
    const float* lin2_w   = (const float*)d_in[12];
    const float* lin2_b   = (const float*)d_in[13];
    const float* g2_w     = (const float*)d_in[14];
    const float* g2_b     = (const float*)d_in[15];
    const int* src = ei;
    const int* dst = ei + N_EDGES;
    float* out = (float*)d_out;

    // workspace layout (~108 MB)
    float* x        = (float*)d_ws;                            // [80000,128] f32
    unsigned short* xwb = (unsigned short*)(x + (size_t)N_NODES * DLAT);  // [80000,128] bf16
    float* gat      = (float*)(xwb + (size_t)N_NODES * DLAT);  // [80000,128] f32 (holds h)
    int*   deg_out  = (int*)(gat + (size_t)N_NODES * DLAT);    // [80000]
    int*   cnt      = deg_out + N_NODES;                       // [80000] count->cursor
    int*   rowptr   = cnt + N_NODES;                           // [80001]
    int*   csr_src  = rowptr + N_NODES + 1;                    // [1e6]
    int*   blocksum = csr_src + N_EDGES;                       // [SCAN_NB]
    float* rsq_deg  = (float*)(blocksum + SCAN_NB);            // [80000]
    unsigned short* mlpWh = (unsigned short*)gat;              // [128][768] (aliases gat)
    unsigned short* mlpWl = mlpWh + (size_t)FEAT_DIM * DLAT;
    unsigned short* wbase = (unsigned short*)(
        (((uintptr_t)(rsq_deg + N_NODES)) + 15) & ~(uintptr_t)15);
    unsigned short* wc1h = wbase;            // 128*128
    unsigned short* wc1l = wc1h + 16384;
    unsigned short* wl1h = wc1l + 16384;     // 64*128
    unsigned short* wl1l = wl1h + 8192;
    unsigned short* wg1h = wl1l + 8192;      // 64*128
    unsigned short* wg1l = wg1h + 8192;
    unsigned short* wc2h = wg1l + 8192;      // 64*64
    unsigned short* wc2l = wc2h + 4096;
    unsigned short* wl2h = wc2l + 4096;      // 64*64
    unsigned short* wl2l = wl2h + 4096;
    unsigned short* wg2h = wl2l + 4096;      // 64*64
    unsigned short* wg2l = wg2h + 4096;

    hipMemsetAsync(deg_out, 0, 2 * N_NODES * sizeof(int), stream);

    // K1: count (edges) || weight prep
    k_count_wtprep<<<NB_COUNT + NB_WT, 256, 0, stream>>>(
        src, dst, deg_out, cnt,
        mlp_w, conv1_w, lin1_w, g1_w, conv2_w, lin2_w, g2_w,
        mlpWh, mlpWl, wc1h, wc1l, wl1h, wl1l, wg1h, wg1l,
        wc2h, wc2l, wl2h, wl2l, wg2h, wg2l);

    // K2: scan_local || mlp GEMM
    k_scanl_mlp<<<SCAN_NB + NB_MLP, 256, 0, stream>>>(
        cnt, rowptr, blocksum, features, mlpWh, mlpWl, mlp_b,
        x + (size_t)NUM_USER * DLAT);

    // K3: scan_blocksums || normcopy (512-thread blocks)
    k_scanb_norm<<<1 + NB_NORM, 512, 0, stream>>>(blocksum, pref, x);

    // K4: scan_add(+cursor zero,+rsqrt) || conv1
    k_scana_conv1<<<SCAN_NB + NB_CONV1, 256, 0, stream>>>(
        rowptr, blocksum, cnt, deg_out, rsq_deg, x, wc1h, wc1l, xwb);

    // K5: CSR fill
    csr_fill_kernel<<<NB_COUNT, 256, 0, stream>>>(src, dst, rowptr, cnt, csr_src);

    // K6-K7: layer 1
    gat_layer_kernel<DLAT><<<(N_NODES + 3) / 4, 256, 0, stream>>>(
        xwb, rowptr, csr_src, rsq_deg, gat);
    combine_mfma_kernel<DLAT><<<N_NODES / 64, 256, 0, stream>>>(
        gat, DLAT, x, DLAT, wg1h, wg1l, wl1h, wl1l, g1_b, lin1_b, id_emb, out, 0);

    // K8-K10: layer 2 (x1 lives in out[:, :64])
    conv2_kernel<<<N_NODES / 64, 256, 0, stream>>>(out, 2 * DID, wc2h, wc2l, xwb, DID);
    gat_layer_kernel<DID><<<(N_NODES + 3) / 4, 256, 0, stream>>>(
        xwb, rowptr, csr_src, rsq_deg, gat);
    combine_mfma_kernel<DID><<<N_NODES / 64, 256, 0, stream>>>(
        gat, DID, out, 2 * DID, wg2h, wg2l, wl2h, wl2l, g2_b, lin2_b, id_emb, out, DID);
}